// Round 5
// baseline (311.640 us; speedup 1.0000x reference)
//
#include <hip/hip_runtime.h>

#define ROW_LEN 128
#define NPAIR (129 * 129)   // (seq, uniq) pairs, each in [0,128]

// Kernel A: precompute MLP(feats(seq,uniq)) for all 16641 pairs -> table[p][32].
__global__ __launch_bounds__(256) void mlp_table_kernel(
    const float* __restrict__ W1, const float* __restrict__ b1,
    const float* __restrict__ W2, const float* __restrict__ b2,
    float* __restrict__ table)
{
    const int tid = blockIdx.x * 256 + threadIdx.x;
    if (tid >= NPAIR * 32) return;
    const int p = tid >> 5;
    const int j = tid & 31;
    const int seq  = p / 129;
    const int uniq = p % 129;
    const float f0 = (float)seq  * (1.0f / 128.0f);
    const float f1 = (float)uniq * (1.0f / 128.0f);
    const float f2 = (seq > 0) ? ((float)uniq / (float)seq) : 0.0f;

    float acc = b2[j];
    #pragma unroll
    for (int jj = 0; jj < 32; ++jj) {
        float h = b1[jj];                 // lane-uniform -> scalar loads
        h = fmaf(f0, W1[jj],      h);
        h = fmaf(f1, W1[32 + jj], h);
        h = fmaf(f2, W1[64 + jj], h);
        h = fmaxf(h, 0.0f);
        acc = fmaf(h, W2[jj * 32 + j], acc);
    }
    table[tid] = fmaxf(acc, 0.0f);
}

// Kernel B: persistent blocks, grid-stride over row-pairs. Two rows per wave
// (lanes 0..31 row A, 32..63 row B), int4 per lane. Bitmap zeroed ONCE per
// block; per iteration only touched words are cleared. Depth-1 prefetch of
// the next pair's data. No __syncthreads (wave-private bitmaps, same-wave DS
// ops are ordered).
__global__ __launch_bounds__(256) void rows_kernel(
    const int* __restrict__ ids, const int* __restrict__ amask,
    const float* __restrict__ table, float* __restrict__ out, long npairs)
{
    __shared__ unsigned bm[8][1024];   // 2 bitmaps per wave (4 KB each)

    const int wave = threadIdx.x >> 6;
    const int lane = threadIdx.x & 63;
    const int half = lane >> 5;        // which row of the pair this lane serves
    const int sh   = lane & 32;        // ballot-half shift for this lane's row

    // zero this wave's two bitmaps once (512 uint4 / 64 lanes = 8 b128 writes)
    uint4* z = (uint4*)bm[wave * 2];
    #pragma unroll
    for (int i = 0; i < 8; ++i) z[lane + i * 64] = make_uint4(0u, 0u, 0u, 0u);
    unsigned* mybm = bm[wave * 2 + half];

    long pair = (long)blockIdx.x * 4 + wave;
    const long stride = (long)gridDim.x * 4;
    if (pair >= npairs) return;

    // prefetch iteration 0
    int4 id4, mk4;
    {
        const long v = pair * 64 + lane;      // pair-chunk = 64 int4
        id4 = ((const int4*)ids)[v];
        mk4 = ((const int4*)amask)[v];
    }

    for (; pair < npairs; pair += stride) {
        // depth-1 prefetch of next iteration (independent of current chain)
        const long nxt = pair + stride;
        int4 id4n = make_int4(0, 0, 0, 0), mk4n = make_int4(0, 0, 0, 0);
        if (nxt < npairs) {
            const long vn = nxt * 64 + lane;
            id4n = ((const int4*)ids)[vn];
            mk4n = ((const int4*)amask)[vn];
        }

        int n0 = 0, n1 = 0, n2 = 0, n3 = 0;
        if (mk4.x != 0) {
            const unsigned t = (unsigned)id4.x, m = 1u << (t & 31u);
            n0 = ((atomicOr(&mybm[t >> 5], m) & m) == 0u);
        }
        if (mk4.y != 0) {
            const unsigned t = (unsigned)id4.y, m = 1u << (t & 31u);
            n1 = ((atomicOr(&mybm[t >> 5], m) & m) == 0u);
        }
        if (mk4.z != 0) {
            const unsigned t = (unsigned)id4.z, m = 1u << (t & 31u);
            n2 = ((atomicOr(&mybm[t >> 5], m) & m) == 0u);
        }
        if (mk4.w != 0) {
            const unsigned t = (unsigned)id4.w, m = 1u << (t & 31u);
            n3 = ((atomicOr(&mybm[t >> 5], m) & m) == 0u);
        }

        // wave totals via ballot; low 32 bits = row A lanes, high 32 = row B
        const unsigned long long s0 = __ballot(mk4.x != 0);
        const unsigned long long s1 = __ballot(mk4.y != 0);
        const unsigned long long s2 = __ballot(mk4.z != 0);
        const unsigned long long s3 = __ballot(mk4.w != 0);
        const unsigned long long u0 = __ballot(n0 != 0);
        const unsigned long long u1 = __ballot(n1 != 0);
        const unsigned long long u2 = __ballot(n2 != 0);
        const unsigned long long u3 = __ballot(n3 != 0);

        const int seq  = __popc((unsigned)(s0 >> sh)) + __popc((unsigned)(s1 >> sh))
                       + __popc((unsigned)(s2 >> sh)) + __popc((unsigned)(s3 >> sh));
        const int uniq = __popc((unsigned)(u0 >> sh)) + __popc((unsigned)(u1 >> sh))
                       + __popc((unsigned)(u2 >> sh)) + __popc((unsigned)(u3 >> sh));

        // clear only the touched words (plain stores; atomics above already
        // retired in wave program order; bitmap is wave-private)
        if (mk4.x != 0) mybm[((unsigned)id4.x) >> 5] = 0u;
        if (mk4.y != 0) mybm[((unsigned)id4.y) >> 5] = 0u;
        if (mk4.z != 0) mybm[((unsigned)id4.z) >> 5] = 0u;
        if (mk4.w != 0) mybm[((unsigned)id4.w) >> 5] = 0u;

        // epilogue: L2-hot 128B gather per row; contiguous 256B store per wave
        const int p = seq * 129 + uniq;
        out[pair * 64 + lane] = table[p * 32 + (lane & 31)];

        id4 = id4n;
        mk4 = mk4n;
    }
}

extern "C" void kernel_launch(void* const* d_in, const int* in_sizes, int n_in,
                              void* d_out, int out_size, void* d_ws, size_t ws_size,
                              hipStream_t stream) {
    const int*   ids   = (const int*)d_in[0];
    const int*   amask = (const int*)d_in[1];
    const float* W1    = (const float*)d_in[2];
    const float* b1    = (const float*)d_in[3];
    const float* W2    = (const float*)d_in[4];
    const float* b2    = (const float*)d_in[5];
    float* out   = (float*)d_out;
    float* table = (float*)d_ws;       // NPAIR*32*4 = 2.13 MB of ws

    const int B = in_sizes[0] / ROW_LEN;              // 262144
    const long npairs = B / 2;                        // 131072

    const int tblThreads = NPAIR * 32;
    mlp_table_kernel<<<(tblThreads + 255) / 256, 256, 0, stream>>>(W1, b1, W2, b2, table);

    // persistent: 5 blocks/CU (LDS-residency limit) x 256 CUs
    const int blocks = 1280;
    rows_kernel<<<blocks, 256, 0, stream>>>(ids, amask, table, out, npairs);
}

// Round 6
// 280.573 us; speedup vs baseline: 1.1107x; 1.1107x over previous
//
#include <hip/hip_runtime.h>

#define ROW_LEN 128
#define NPAIR (129 * 129)   // (seq, uniq) pairs, each in [0,128]

// Kernel A: precompute MLP(feats(seq,uniq)) for all 16641 pairs -> table[p][32].
__global__ __launch_bounds__(256) void mlp_table_kernel(
    const float* __restrict__ W1, const float* __restrict__ b1,
    const float* __restrict__ W2, const float* __restrict__ b2,
    float* __restrict__ table)
{
    const int tid = blockIdx.x * 256 + threadIdx.x;
    if (tid >= NPAIR * 32) return;
    const int p = tid >> 5;
    const int j = tid & 31;
    const int seq  = p / 129;
    const int uniq = p % 129;
    const float f0 = (float)seq  * (1.0f / 128.0f);
    const float f1 = (float)uniq * (1.0f / 128.0f);
    const float f2 = (seq > 0) ? ((float)uniq / (float)seq) : 0.0f;

    float acc = b2[j];
    #pragma unroll
    for (int jj = 0; jj < 32; ++jj) {
        float h = b1[jj];                 // lane-uniform -> scalar loads
        h = fmaf(f0, W1[jj],      h);
        h = fmaf(f1, W1[32 + jj], h);
        h = fmaf(f2, W1[64 + jj], h);
        h = fmaxf(h, 0.0f);
        acc = fmaf(h, W2[jj * 32 + j], acc);
    }
    table[tid] = fmaxf(acc, 0.0f);
}

// Kernel B: ONE row per wave (int2 per lane), 4 waves/block, 16 KB LDS
// -> 8 blocks/CU = 32 waves/CU (vs R4's 20). Per-row DS work identical to
// R4: 4x b128 zero + 2 scattered atomicOr. seq/uniq via ballot+popcll
// (zero DS ops). No __syncthreads (wave-private bitmap, same-wave DS order).
__global__ __launch_bounds__(256, 8) void rows_kernel(
    const int* __restrict__ ids, const int* __restrict__ amask,
    const float* __restrict__ table, float* __restrict__ out, int B)
{
    __shared__ unsigned bm[4][1024];   // one 4 KB bitmap per wave

    const int wave = threadIdx.x >> 6;
    const int lane = threadIdx.x & 63;
    const long row = (long)blockIdx.x * 4 + wave;
    if (row >= B) return;              // B % 4 == 0; cosmetic

    // issue global loads first so bitmap zeroing overlaps HBM latency.
    // Row = 64 int2; lane i covers ints [2i, 2i+2).
    const long v = row * 64 + lane;
    const int2 id2 = ((const int2*)ids)[v];
    const int2 mk2 = ((const int2*)amask)[v];

    // zero own bitmap: 1024 words = 256 uint4 -> 4 ds_write_b128 per lane
    uint4* z = (uint4*)bm[wave];
    #pragma unroll
    for (int i = 0; i < 4; ++i) z[lane + i * 64] = make_uint4(0u, 0u, 0u, 0u);
    unsigned* mybm = bm[wave];

    int n0 = 0, n1 = 0;                // "new token" flags
    if (mk2.x != 0) {
        const unsigned t = (unsigned)id2.x, m = 1u << (t & 31u);
        n0 = ((atomicOr(&mybm[t >> 5], m) & m) == 0u);
    }
    if (mk2.y != 0) {
        const unsigned t = (unsigned)id2.y, m = 1u << (t & 31u);
        n1 = ((atomicOr(&mybm[t >> 5], m) & m) == 0u);
    }

    // wave totals purely via ballot + popcount: no DS reduction ops
    const unsigned long long s0 = __ballot(mk2.x != 0);
    const unsigned long long s1 = __ballot(mk2.y != 0);
    const unsigned long long u0 = __ballot(n0 != 0);
    const unsigned long long u1 = __ballot(n1 != 0);

    const int seq  = __popcll(s0) + __popcll(s1);
    const int uniq = __popcll(u0) + __popcll(u1);

    // epilogue: 128B L2-hot table gather, contiguous 128B store
    const int p = seq * 129 + uniq;
    if (lane < 32) out[row * 32 + lane] = table[p * 32 + lane];
}

extern "C" void kernel_launch(void* const* d_in, const int* in_sizes, int n_in,
                              void* d_out, int out_size, void* d_ws, size_t ws_size,
                              hipStream_t stream) {
    const int*   ids   = (const int*)d_in[0];
    const int*   amask = (const int*)d_in[1];
    const float* W1    = (const float*)d_in[2];
    const float* b1    = (const float*)d_in[3];
    const float* W2    = (const float*)d_in[4];
    const float* b2    = (const float*)d_in[5];
    float* out   = (float*)d_out;
    float* table = (float*)d_ws;       // NPAIR*32*4 = 2.13 MB of ws

    const int B = in_sizes[0] / ROW_LEN;              // 262144

    const int tblThreads = NPAIR * 32;
    mlp_table_kernel<<<(tblThreads + 255) / 256, 256, 0, stream>>>(W1, b1, W2, b2, table);

    // 1 row per wave, 4 waves per block -> 4 rows per block
    rows_kernel<<<(B + 3) / 4, 256, 0, stream>>>(ids, amask, table, out, B);
}